// Round 8
// baseline (378.041 us; speedup 1.0000x reference)
//
#include <hip/hip_runtime.h>

// LIF forward recurrence, bit-exact vs the numpy fp32 reference.
//
// Reference per step (exact op order, correctly rounded, no contraction):
//   th   = 1 + 1.5*a
//   v    = (v - v/20) + I_t
//   s    = (v >= th) ? 1 : 0        // STE forward == s_hard exactly (Sterbenz)
//   snum += s                       // exact {0,1} integer cumsum
//   v    = s ? -0.5 : v
//   a    = (a - a/100) + s
//
// R1: LDS 64x64 tile transpose killed 3x HBM write amplification.
// R2: Markstein 3-op constant division (provably == __fdiv_rn for d=20,100).
// R4-R7: producer/consumer waves, barriers, swizzled b128 LDS, quad buffers.
// R8/R9: stateless 2-helper flush: NEUTRAL => helpers have ~3x slack.
// R10: packed-f32 dual issue, slice 46 -> 38 us (375.4 total).
// R11: direct global stores: slice 70 us. Store coalescing is load-bearing.
// R12: flush merged into compute wave: slice 45 us. Wait-bearing ops must
//      live in helper waves.
// R13: revert to R10: reproduced (376.1).
// R14: compute stripped to 11.5 issue slots/step (cumsum -> helper-1, se
//      stream -> helper-2, de-packed state update): NEUTRAL (376.7).
//      => compute wave is LATENCY-bound on the loop-carried chain, not
//      issue-bound. But nominal chain = 24 cyc (6 x 4) vs measured ~44.5.
// R15 (this): hypothesis test -- VOP3P dep-to-dep forwarding may be ~8 cyc
//   (m07 measured 4 cyc for SCALAR v_fma only; no pk number exists). Then
//   the vn cycle = 4 pk x 8 + cndmask 4 + add 4 = 40 ~= 44.5 measured.
//   Test: de-pack both decay chains to the original R2-proven scalar ops
//   (bit-exactness inherited). Issue 11.5 -> ~15.25 slots = 30.5 cyc, still
//   below measured 44.5 => safe if hypothesis false (neutral), -10..14
//   cyc/step if true (slice ~27-29 us). Structure identical to R14.

#define LIF_L  2048
#define TILE   64
#define NTILES (LIF_L / TILE)   // 32

// Compile-time, correctly rounded: rn(-0.5/20) and rn(-0.5 - that).
constexpr float kR20 = -0.5f / 20.0f;
constexpr float kC0  = -0.5f - kR20;

__device__ __forceinline__ void barrier_lds_only() {
    asm volatile("s_waitcnt lgkmcnt(0)\n\ts_barrier" ::: "memory");
}

// One step, all-scalar (R2-proven op sequence). vn = membrane AFTER input
// add (what the threshold sees). Inext = input of the NEXT step.
//   fire = vn >= th; s = fire ? 1 : 0
//   d    = __fdiv_rn(vn,20) via Markstein (q0,r,d)
//   dec  = rn(vn - d)
//   sel  = fire ? kC0 : dec         (select-before-add, == two-add+select)
//   vn'  = rn(sel + Inext)
//   da   = __fdiv_rn(a,100) via Markstein (qa,ra,da)
//   ap   = rn(a - da);  a' = rn(ap + s)   (s in {0,1}, ap >= 0)
//   th'  = rn(1 + rn(1.5*a'))       (reference order mul-then-add)
__device__ __forceinline__ float lif_step(float Inext, float& vn, float& a,
                                          float& th) {
    bool fire = (vn >= th);
    float s = fire ? 1.0f : 0.0f;
    float q0 = __fmul_rn(vn, 0.05f);
    float r  = __fmaf_rn(-20.0f, q0, vn);
    float d  = __fmaf_rn(r, 0.05f, q0);        // == __fdiv_rn(vn, 20)
    float dec = __fsub_rn(vn, d);
    float sel = fire ? kC0 : dec;
    vn = __fadd_rn(sel, Inext);
    float qa = __fmul_rn(a, 0.01f);
    float ra = __fmaf_rn(-100.0f, qa, a);
    float da = __fmaf_rn(ra, 0.01f, qa);       // == __fdiv_rn(a, 100)
    float ap = __fsub_rn(a, da);
    a = __fadd_rn(ap, s);
    th = __fadd_rn(1.0f, __fmul_rn(1.5f, a));  // reference order
    return s;
}

// Swizzled LDS float index for (row, 16B-group g): aligned b128, conflict-free.
__device__ __forceinline__ int sw_idx(int row, int g) {
    return row * 64 + (((g) ^ (row & 15)) << 2);
}

__global__ __launch_bounds__(192, 1) void lif_fwd(const float* __restrict__ I,
                                                  float* __restrict__ spikes,
                                                  float* __restrict__ series) {
    __shared__ float sp_tile[4][64 * 64];      // quad-buffered spike tiles (64 KB)
    __shared__ float se_tile[4][64 * 64];      // quad-buffered series tiles (64 KB)

    const int tid  = threadIdx.x;
    const int wave = tid >> 6;                 // 0 = compute, 1 = cumsum, 2 = flush
    const int lane = tid & 63;
    const int row0 = blockIdx.x * 64;

    const float4* __restrict__ I4 =
        reinterpret_cast<const float4*>(I + (size_t)(row0 + lane) * LIF_L);

    // compute-wave state
    float vn = 0.0f, a = 0.0f, th = 1.0f;
    float4 bufA[16], bufB[16];
    // helper-1 state: series carry, lane = row, lives here all 2048 steps
    float carry = 0.0f;

    if (wave == 0) {
        #pragma unroll
        for (int i = 0; i < 16; ++i) bufA[i] = I4[i];
        #pragma unroll
        for (int i = 0; i < 16; ++i) bufB[i] = I4[16 + i];
    }

    // Compute: spikes only. ~15 scalar VALU + 0.25 ds_write per step.
    auto compute_tile = [&](const float4* buf, float nx0, float* sp) {
        #pragma unroll
        for (int c = 0; c < 16; ++c) {
            float4 in = buf[c];
            float nxt = (c < 15) ? buf[c + 1].x : nx0;
            float4 os;
            os.x = lif_step(in.y, vn, a, th);
            os.y = lif_step(in.z, vn, a, th);
            os.z = lif_step(in.w, vn, a, th);
            os.w = lif_step(nxt,  vn, a, th);
            *reinterpret_cast<float4*>(&sp[sw_idx(lane, c)]) = os;  // ds_write_b128
        }
    };

    // Helper-1: per-row cumsum (lane = row), exact {0,1} adds, b128 LDS ops.
    auto cumsum_tile = [&](const float* sp, float* se) {
        #pragma unroll
        for (int c = 0; c < 16; ++c) {
            int ix = sw_idx(lane, c);
            float4 sv = *reinterpret_cast<const float4*>(&sp[ix]);
            float4 nv;
            carry = __fadd_rn(carry, sv.x); nv.x = carry;
            carry = __fadd_rn(carry, sv.y); nv.y = carry;
            carry = __fadd_rn(carry, sv.z); nv.z = carry;
            carry = __fadd_rn(carry, sv.w); nv.w = carry;
            *reinterpret_cast<float4*>(&se[ix]) = nv;
        }
    };

    // Helper-2: transposed coalesced flush of one stream; instr i = 4 rows x 256 B.
    auto flush_stream = [&](int tkt, const float* buf, float* gbase) {
        const size_t colbase = (size_t)tkt * TILE;
        #pragma unroll
        for (int i = 0; i < 16; ++i) {
            int row = i * 4 + (lane >> 4);
            int g   = lane & 15;
            int ix  = sw_idx(row, g);
            float4 v = *reinterpret_cast<const float4*>(&buf[ix]);
            size_t gaddr = (size_t)(row0 + row) * LIF_L + colbase + (size_t)g * 4;
            *reinterpret_cast<float4*>(gbase + gaddr) = v;
        }
    };

    // init: vn_0 = rn(rn(0 - rn(0/20)) + I_0) = I_0 exactly; a_0 = 0
    if (wave == 0) vn = bufA[0].x;

    // Pair loop. Pair p: compute -> sp{2p,2p+1}; helper-1 cumsums sp{2p-2,2p-1}
    // -> se (same slots); helper-2 flushes sp{2p-2,2p-1} and se{2p-4,2p-3}.
    // Slot disjointness mod 4: compute writes {2p,2p+1}; helper-1 touches
    // {2p+2,2p+3}; helper-2's se reads {2p,2p+1} were written during pair p-1
    // (one barrier ago). One barrier per pair.
    for (int p = 0; p < NTILES / 2; ++p) {
        const int kt = 2 * p;
        if (wave == 0) {
            compute_tile(bufA, bufB[0].x, sp_tile[kt & 3]);
            if (kt + 2 < NTILES) {
                #pragma unroll
                for (int i = 0; i < 16; ++i) bufA[i] = I4[(kt + 2) * 16 + i];
            }
            float nx0 = (kt + 2 < NTILES) ? bufA[0].x : 0.0f;
            compute_tile(bufB, nx0, sp_tile[(kt + 1) & 3]);
            if (kt + 3 < NTILES) {
                #pragma unroll
                for (int i = 0; i < 16; ++i) bufB[i] = I4[(kt + 3) * 16 + i];
            }
        } else if (wave == 1) {
            if (p > 0) {
                cumsum_tile(sp_tile[(kt - 2) & 3], se_tile[(kt - 2) & 3]);
                cumsum_tile(sp_tile[(kt - 1) & 3], se_tile[(kt - 1) & 3]);
            }
        } else {
            if (p > 0) {
                flush_stream(kt - 2, sp_tile[(kt - 2) & 3], spikes);
                flush_stream(kt - 1, sp_tile[(kt - 1) & 3], spikes);
            }
            if (p > 1) {
                flush_stream(kt - 4, se_tile[(kt - 4) & 3], series);
                flush_stream(kt - 3, se_tile[(kt - 3) & 3], series);
            }
        }
        barrier_lds_only();
    }
    // Tail. Outstanding: cumsum 30,31 (slots 2,3); flush sp 30,31; se 28,29
    // (slots 0,1, written during p=15); then se 30,31 after a barrier.
    if (wave == 1) {
        cumsum_tile(sp_tile[2], se_tile[2]);           // tile 30
        cumsum_tile(sp_tile[3], se_tile[3]);           // tile 31
    } else if (wave == 2) {
        flush_stream(NTILES - 2, sp_tile[2], spikes);
        flush_stream(NTILES - 1, sp_tile[3], spikes);
        flush_stream(NTILES - 4, se_tile[0], series);
        flush_stream(NTILES - 3, se_tile[1], series);
    }
    barrier_lds_only();
    if (wave == 1) {
        flush_stream(NTILES - 2, se_tile[2], series);
    } else if (wave == 2) {
        flush_stream(NTILES - 1, se_tile[3], series);
    }
}

extern "C" void kernel_launch(void* const* d_in, const int* in_sizes, int n_in,
                              void* d_out, int out_size, void* d_ws, size_t ws_size,
                              hipStream_t stream) {
    const float* I = (const float*)d_in[0];
    const int B = in_sizes[0] / LIF_L;                  // 16384
    float* spikes = (float*)d_out;                      // (B, L)
    float* series = (float*)d_out + (size_t)B * LIF_L;  // (B, L)

    const int threads = 192;                            // compute + cumsum + flush
    const int blocks = B / 64;                          // 256 blocks, 64 rows each
    lif_fwd<<<blocks, threads, 0, stream>>>(I, spikes, series);
}

// Round 9
// 373.310 us; speedup vs baseline: 1.0127x; 1.0127x over previous
//
#include <hip/hip_runtime.h>

// LIF forward recurrence, bit-exact vs the numpy fp32 reference.
//
// Reference per step (exact op order, correctly rounded, no contraction):
//   th   = 1 + 1.5*a
//   v    = (v - v/20) + I_t
//   s    = (v >= th) ? 1 : 0        // STE forward == s_hard exactly (Sterbenz)
//   snum += s                       // exact {0,1} integer cumsum
//   v    = s ? -0.5 : v
//   a    = (a - a/100) + s
//
// R1: LDS 64x64 tile transpose killed 3x HBM write amplification.
// R2: Markstein 3-op constant division (provably == __fdiv_rn for d=20,100).
// R4-R7: producer/consumer waves, barriers, swizzled b128 LDS, quad buffers.
// R8/R9: stateless 2-helper flush: NEUTRAL => helpers have ~3x slack; the
//      compute wave's serial issue stream is the wall clock.
// R10: packed-f32 dual issue (v_pk_mul/fma/add, per-component rn == scalar,
//      bit-exact). 16 -> 11 ops/step. Slice ~38 us, 375.4 total == SESSION
//      BEST (reproduced as R13: 376.1).
// R11: direct global stores (no LDS): 407. Store coalescing load-bearing.
// R12: flush merged into compute wave: 381.9. Wait-bearing ops must live in
//      helper waves (waitcnt blocks the whole wave).
// R14: compute stripped to 11.5 slots/step (cumsum->helper-1, se->helper-2,
//      de-packed update): NEUTRAL (376.7).
// R15: all-scalar de-pack (VOP3P-latency hypothesis test): NEUTRAL (378.0).
//      Hypothesis refuted: pk forwarding == scalar forwarding.
// R16 (this): revert to the measured-best R10/R13 kernel. CLOSED MODEL:
//   per-step wall ~44 cyc ~= 2x the 23-cyc issue floor; latency exposure ~=
//   issue time, so every rebalancing nulls by arithmetic: 2-row/lane
//   interleave => 2x steps/wave (94k vs 91k cyc); 2 compute waves/SIMD =>
//   same via shared issue port; chain is already cross-step-overlapped
//   (~16-20 cyc/step nominal, below measured); 11 ops/step is within 1 op
//   of the bit-exact floor. Remaining upside ~4% of dur_us (kernel is ~12%
//   of the measurement; 2 poison fills are 88% and vary +/-2% per run).
//   Serial nonlinear recurrence (threshold+reset => no associative scan):
//   structural floor.

#define LIF_L  2048
#define TILE   64
#define NTILES (LIF_L / TILE)   // 32

typedef float f32x2 __attribute__((ext_vector_type(2)));

// Compile-time, correctly rounded: rn(-0.5/20) and rn(-0.5 - that).
constexpr float kR20 = -0.5f / 20.0f;
constexpr float kC0  = -0.5f - kR20;

__device__ __forceinline__ void barrier_lds_only() {
    asm volatile("s_waitcnt lgkmcnt(0)\n\ts_barrier" ::: "memory");
}

// One step. x = (vn, a): vn = membrane AFTER input add (what the threshold
// sees), a = adaptation. Inext = input of the NEXT step. Returns spike {0,1}.
//
// Bit-exactness vs the proven scalar version:
//   q   = x*C1                    : per-elem rn mul == {__fmul_rn(vn,.05), __fmul_rn(a,.01)}
//   r   = fma(C2,q,x)             : exact remainders {fma(-20,q0,vn), fma(-100,qa,a)}
//   d   = fma(r,C1,q)             : Markstein => d == {__fdiv_rn(vn,20), __fdiv_rn(a,100)}
//   dec = fma(d,-1,x)             : exact product => single-rounded rn(x-d) == __fsub_rn
//   dec.x = fire ? kC0 : dec.x    : select-before-add (distributes over final rn add)
//   x'  = dec + (Inext, s)        : {rn(sel+Inext), rn(ap+s)}; s in {0,1}, ap >= 0
//   th  = rn(1 + rn(1.5*a'))      : reference order mul-then-add
__device__ __forceinline__ float lif_step(float Inext, f32x2& x, float& th,
                                          float& carry) {
    const f32x2 C1 = {0.05f, 0.01f};
    const f32x2 C2 = {-20.0f, -100.0f};
    const f32x2 M1 = {-1.0f, -1.0f};
    bool fire = (x.x >= th);
    float s = fire ? 1.0f : 0.0f;
    f32x2 q   = x * C1;                              // v_pk_mul_f32
    f32x2 r   = __builtin_elementwise_fma(C2, q, x); // v_pk_fma_f32
    f32x2 d   = __builtin_elementwise_fma(r, C1, q); // v_pk_fma_f32 (exact divs)
    f32x2 dec = __builtin_elementwise_fma(d, M1, x); // v_pk_fma_f32 (= x - d)
    dec.x = fire ? kC0 : dec.x;                      // cndmask on low half
    f32x2 t = {Inext, s};
    x = dec + t;                                     // v_pk_add_f32
    carry = __fadd_rn(carry, s);                     // exact {0,1} cumsum
    th = __fadd_rn(1.0f, __fmul_rn(1.5f, x.y));      // reference order
    return s;
}

// Swizzled LDS float index for (row, 16B-group g): aligned b128, conflict-free.
__device__ __forceinline__ int sw_idx(int row, int g) {
    return row * 64 + (((g) ^ (row & 15)) << 2);
}

__global__ __launch_bounds__(192, 1) void lif_fwd(const float* __restrict__ I,
                                                  float* __restrict__ spikes,
                                                  float* __restrict__ series) {
    __shared__ float sp_tile[4][64 * 64];      // quad-buffered spike tiles (64 KB)
    __shared__ float se_tile[4][64 * 64];      // quad-buffered series tiles (64 KB)

    const int tid  = threadIdx.x;
    const int wave = tid >> 6;                 // 0 = compute, 1/2 = helpers
    const int lane = tid & 63;
    const int row0 = blockIdx.x * 64;

    const float4* __restrict__ I4 =
        reinterpret_cast<const float4*>(I + (size_t)(row0 + lane) * LIF_L);

    // compute-wave state: x = (vn, a) packed for v_pk_* dual issue
    f32x2 x = {0.0f, 0.0f};
    float th = 1.0f, carry = 0.0f;
    float4 bufA[16], bufB[16];

    if (wave == 0) {
        #pragma unroll
        for (int i = 0; i < 16; ++i) bufA[i] = I4[i];
        #pragma unroll
        for (int i = 0; i < 16; ++i) bufB[i] = I4[16 + i];
    }

    auto compute_tile = [&](const float4* buf, float nx0, float* sp, float* se) {
        #pragma unroll
        for (int c = 0; c < 16; ++c) {
            float4 in = buf[c];
            float nxt = (c < 15) ? buf[c + 1].x : nx0;
            float4 os, oc;
            os.x = lif_step(in.y, x, th, carry); oc.x = carry;
            os.y = lif_step(in.z, x, th, carry); oc.y = carry;
            os.z = lif_step(in.w, x, th, carry); oc.z = carry;
            os.w = lif_step(nxt,  x, th, carry); oc.w = carry;
            *reinterpret_cast<float4*>(&sp[sw_idx(lane, c)]) = os;  // ds_write_b128
            *reinterpret_cast<float4*>(&se[sw_idx(lane, c)]) = oc;  // ds_write_b128
        }
    };

    // Stateless flush: transposed coalesced stores, instr i covers 4 rows x 256 B.
    auto flush_tile = [&](int tkt, const float* sp, const float* se) {
        const size_t colbase = (size_t)tkt * TILE;
        #pragma unroll
        for (int i = 0; i < 16; ++i) {
            int row = i * 4 + (lane >> 4);
            int g   = lane & 15;
            int ix  = sw_idx(row, g);
            float4 vs = *reinterpret_cast<const float4*>(&sp[ix]);
            float4 ve = *reinterpret_cast<const float4*>(&se[ix]);
            size_t gaddr = (size_t)(row0 + row) * LIF_L + colbase + (size_t)g * 4;
            *reinterpret_cast<float4*>(spikes + gaddr) = vs;
            *reinterpret_cast<float4*>(series + gaddr) = ve;
        }
    };

    // init: vn_0 = rn(rn(0 - rn(0/20)) + I_0) = I_0 exactly; a_0 = 0
    if (wave == 0) x.x = bufA[0].x;

    // Pair loop: iteration p computes tiles {2p, 2p+1} into buffer set
    // {(2p)&3, (2p+1)&3}; helpers consume pair p-1 (the other, disjoint set):
    // wave1 flushes tile 2p-2, wave2 flushes tile 2p-1. One barrier per pair.
    for (int p = 0; p < NTILES / 2; ++p) {
        const int kt = 2 * p;
        if (wave == 0) {
            compute_tile(bufA, bufB[0].x, sp_tile[kt & 3], se_tile[kt & 3]);
            if (kt + 2 < NTILES) {
                #pragma unroll
                for (int i = 0; i < 16; ++i) bufA[i] = I4[(kt + 2) * 16 + i];
            }
            float nx0 = (kt + 2 < NTILES) ? bufA[0].x : 0.0f;
            compute_tile(bufB, nx0, sp_tile[(kt + 1) & 3], se_tile[(kt + 1) & 3]);
            if (kt + 3 < NTILES) {
                #pragma unroll
                for (int i = 0; i < 16; ++i) bufB[i] = I4[(kt + 3) * 16 + i];
            }
        } else if (p > 0) {
            if (wave == 1) {
                flush_tile(kt - 2, sp_tile[(kt - 2) & 3], se_tile[(kt - 2) & 3]);
            } else {
                flush_tile(kt - 1, sp_tile[(kt - 1) & 3], se_tile[(kt - 1) & 3]);
            }
        }
        barrier_lds_only();
    }
    // tail: last pair (tiles 30, 31 live in buffer sets 2, 3)
    if (wave == 1) {
        flush_tile(NTILES - 2, sp_tile[(NTILES - 2) & 3], se_tile[(NTILES - 2) & 3]);
    } else if (wave == 2) {
        flush_tile(NTILES - 1, sp_tile[(NTILES - 1) & 3], se_tile[(NTILES - 1) & 3]);
    }
}

extern "C" void kernel_launch(void* const* d_in, const int* in_sizes, int n_in,
                              void* d_out, int out_size, void* d_ws, size_t ws_size,
                              hipStream_t stream) {
    const float* I = (const float*)d_in[0];
    const int B = in_sizes[0] / LIF_L;                  // 16384
    float* spikes = (float*)d_out;                      // (B, L)
    float* series = (float*)d_out + (size_t)B * LIF_L;  // (B, L)

    const int threads = 192;                            // 3 waves: compute + 2 helpers
    const int blocks = B / 64;                          // 256 blocks, 64 rows each
    lif_fwd<<<blocks, threads, 0, stream>>>(I, spikes, series);
}